// Round 5
// baseline (182.176 us; speedup 1.0000x reference)
//
#include <hip/hip_runtime.h>

// Sparse 3D submanifold conv — gather formulation + bf16 MFMA.
//   prep_all:  feats fp32->bf16 (+zero row), weights -> B-frag swizzled table,
//              nbrt fill: slots 0..25,27 = -1, slot 26 = row (center identity).
//   prep_nbr:  nbrt[omap[s,m]*28 + s] = imap[s,m]  (dsts unique per slice).
//   spconv_main: 16 rows/wave (one 16x16 tile), 27 uniform taps; per-lane
//              neighbor indices loaded as 7 coalesced int4 in the prologue so
//              all A-gathers are independent; 8 MFMAs/tap; one store per elem.

#define N_PTS 100000
#define MPAD  60000
#define C     64
#define NSL   27          // taps 0..25 = offsets, 26 = center (kernel[13])
#define NBS   28          // nbrt row stride (ints): 27 taps + pad, 112 B

typedef short bf16x8 __attribute__((ext_vector_type(8)));   // 8 x bf16 bits (4 VGPRs)
typedef float f32x4  __attribute__((ext_vector_type(4)));

static __device__ inline unsigned short f2bf(float x) {
    unsigned int u = __float_as_uint(x);
    u += 0x7fffu + ((u >> 16) & 1u);
    return (unsigned short)(u >> 16);
}

// workspace layout (bytes)
#define FEATS16_BYTES ((size_t)(N_PTS + 1) * C * 2)             // 12,800,128 (+1 zero row)
#define WFRAG_OFF     (((FEATS16_BYTES) + 255) & ~(size_t)255)  // 12,800,256
#define WFRAG_BYTES   ((size_t)NSL * 2 * 4 * 64 * 16)           // 221,184
#define NBRT_OFF      (WFRAG_OFF + WFRAG_BYTES)                 // 13,021,440
#define NBRT_BYTES    ((size_t)N_PTS * NBS * 4)                 // 11,200,000

// flat work ranges for prep_all
#define FEAT_ITEMS 800008                       // 800000 bf16x8 + 8 zero-row vectors
#define WF_ITEMS   (NSL * 2 * 4 * 64)           // 13824
#define NBRT_ITEMS (N_PTS * NBS / 4)            // 700000 int4 fills
#define PREP_TOTAL (FEAT_ITEMS + WF_ITEMS + NBRT_ITEMS)

__global__ __launch_bounds__(256) void prep_all(const float* __restrict__ feats,
                                                const float* __restrict__ kern,
                                                unsigned short* __restrict__ f16,
                                                unsigned short* __restrict__ wf,
                                                int* __restrict__ nbrt) {
    const int idx = blockIdx.x * 256 + threadIdx.x;
    if (idx < FEAT_ITEMS) {
        // feats fp32 -> bf16, 8 elems/thread; last 8 items write the zero row
        bf16x8* dst = (bf16x8*)f16;
        if (idx < FEAT_ITEMS - 8) {
            const float4* src = (const float4*)feats;
            const float4 a = src[2 * idx];
            const float4 b = src[2 * idx + 1];
            bf16x8 v;
            v[0] = (short)f2bf(a.x); v[1] = (short)f2bf(a.y);
            v[2] = (short)f2bf(a.z); v[3] = (short)f2bf(a.w);
            v[4] = (short)f2bf(b.x); v[5] = (short)f2bf(b.y);
            v[6] = (short)f2bf(b.z); v[7] = (short)f2bf(b.w);
            dst[idx] = v;
        } else {
            dst[idx] = (bf16x8){0, 0, 0, 0, 0, 0, 0, 0};
        }
    } else if (idx < FEAT_ITEMS + WF_ITEMS) {
        // weights -> B-frag table: lane (q,t) holds B[k=32kk+8q+j][n=16ct+t]
        const int w = idx - FEAT_ITEMS;
        const int lane = w & 63;
        const int rest = w >> 6;
        const int ct = rest & 3;
        const int kk = (rest >> 2) & 1;
        const int s  = rest >> 3;
        const int q = lane >> 4, t = lane & 15;
        const int ksrc = (s == 26) ? 13 : (s + (s >= 13 ? 1 : 0));
        const int k0 = kk * 32 + q * 8;
        const int n  = ct * 16 + t;
        const float* wp = kern + (size_t)ksrc * 4096 + n;
        bf16x8 v;
        #pragma unroll
        for (int j = 0; j < 8; ++j) v[j] = (short)f2bf(wp[(size_t)(k0 + j) * 64]);
        ((bf16x8*)wf)[w] = v;
    } else {
        // nbrt fill: int4 #v of row r; slots 24..27 get (-1,-1,row,-1)
        const int k = idx - (FEAT_ITEMS + WF_ITEMS);
        if (k < NBRT_ITEMS) {
            const int v = k % 7;
            const int r = k / 7;
            int4 val = make_int4(-1, -1, -1, -1);
            if (v == 6) val.z = r;          // slot 26 = center identity
            ((int4*)nbrt)[k] = val;
        }
    }
}

// scatter: nbrt[omap[s,m]*28 + s] = imap[s,m]; int4-vectorized map reads
__global__ __launch_bounds__(256) void prep_nbr(const int* __restrict__ imap,
                                                const int* __restrict__ omap,
                                                int* __restrict__ nbrt) {
    const int v = blockIdx.x * 256 + threadIdx.x;     // vector index (4 m's)
    const int s = blockIdx.y;
    if (v >= MPAD / 4) return;
    const int4 iv = ((const int4*)(imap + (size_t)s * MPAD))[v];
    const int4 ov = ((const int4*)(omap + (size_t)s * MPAD))[v];
    if (iv.x >= 0) nbrt[(size_t)ov.x * NBS + s] = iv.x;
    if (iv.y >= 0) nbrt[(size_t)ov.y * NBS + s] = iv.y;
    if (iv.z >= 0) nbrt[(size_t)ov.z * NBS + s] = iv.z;
    if (iv.w >= 0) nbrt[(size_t)ov.w * NBS + s] = iv.w;
}

// ---- main MFMA gather kernel: 4 waves/block, 16 rows/wave ----
__global__ __launch_bounds__(256) void spconv_main(const unsigned short* __restrict__ f16,
                                                   const unsigned short* __restrict__ wf,
                                                   const int* __restrict__ nbrt,
                                                   float* __restrict__ out) {
    const int lane = threadIdx.x & 63;
    const int wave = threadIdx.x >> 6;
    const int q = lane >> 4, t = lane & 15;
    const int R0 = (blockIdx.x * 4 + wave) * 16;
    const int row = R0 + t;
    const bool inb = (row < N_PTS);

    const bf16x8* wfv = (const bf16x8*)wf;
    const bf16x8* fv  = (const bf16x8*)f16;

    // prologue: this lane's 27 neighbor indices, 7 coalesced int4 loads
    int4 jv[7];
    {
        const int safe_row = inb ? row : 0;
        const int4* jp = (const int4*)(nbrt + (size_t)safe_row * NBS);
        #pragma unroll
        for (int i = 0; i < 7; ++i) jv[i] = jp[i];
    }
    const int* jarr = (const int*)jv;

    f32x4 acc[4];
    #pragma unroll
    for (int c = 0; c < 4; ++c) acc[c] = (f32x4){0.f, 0.f, 0.f, 0.f};

    #pragma unroll
    for (int s = 0; s < NSL; ++s) {
        const int j  = inb ? jarr[s] : -1;
        const int jz = ((unsigned)j < (unsigned)N_PTS) ? j : N_PTS;   // invalid -> zero row
        const bf16x8* ar = fv + (size_t)jz * 8;
        const bf16x8 A0 = ar[q];        // A[row=t][k = 8q + j],  k in [0,32)
        const bf16x8 A1 = ar[4 + q];    // k in [32,64)
        #pragma unroll
        for (int ct = 0; ct < 4; ++ct)
            acc[ct] = __builtin_amdgcn_mfma_f32_16x16x32_bf16(
                A0, wfv[s * 512 + ct * 64 + lane], acc[ct], 0, 0, 0);
        #pragma unroll
        for (int ct = 0; ct < 4; ++ct)
            acc[ct] = __builtin_amdgcn_mfma_f32_16x16x32_bf16(
                A1, wfv[s * 512 + 256 + ct * 64 + lane], acc[ct], 0, 0, 0);
    }

    // epilogue: D layout col = t, row = 4q + reg
    #pragma unroll
    for (int i = 0; i < 4; ++i) {
        const int r = R0 + 4 * q + i;
        if (r < N_PTS) {
            #pragma unroll
            for (int ct = 0; ct < 4; ++ct)
                out[(size_t)r * C + ct * 16 + t] = acc[ct][i];
        }
    }
}

extern "C" void kernel_launch(void* const* d_in, const int* in_sizes, int n_in,
                              void* d_out, int out_size, void* d_ws, size_t ws_size,
                              hipStream_t stream) {
    const float* feats = (const float*)d_in[0];
    const float* kern  = (const float*)d_in[1];
    const int*   imap  = (const int*)d_in[2];
    const int*   omap  = (const int*)d_in[3];

    char* ws = (char*)d_ws;
    unsigned short* f16  = (unsigned short*)ws;
    unsigned short* wfr  = (unsigned short*)(ws + WFRAG_OFF);
    int*            nbrt = (int*)(ws + NBRT_OFF);

    prep_all<<<dim3((PREP_TOTAL + 255) / 256), dim3(256), 0, stream>>>(
        feats, kern, f16, wfr, nbrt);
    prep_nbr<<<dim3((MPAD / 4 + 255) / 256, 26), dim3(256), 0, stream>>>(
        imap, omap, nbrt);
    spconv_main<<<dim3((N_PTS + 63) / 64), dim3(256), 0, stream>>>(
        f16, wfr, nbrt, (float*)d_out);
}